// Round 2
// baseline (64.415 us; speedup 1.0000x reference)
//
#include <hip/hip_runtime.h>
#include <hip/hip_bf16.h>
#include <cstdint>

#define NROWS 262144
#define DIM 128
#define HID 64
#define NG 4
#define NP 4

typedef float f32x4 __attribute__((ext_vector_type(4)));
typedef short s16x8 __attribute__((ext_vector_type(8)));
typedef unsigned short u16x8 __attribute__((ext_vector_type(8)));
typedef unsigned int u32x2 __attribute__((ext_vector_type(2)));

__device__ __forceinline__ unsigned short cvbf(float f){
  unsigned u = __float_as_uint(f);
  return (unsigned short)((u + 0x8000u) >> 16);   // round-half-up to bf16
}

__device__ __forceinline__ void ldsload16(const void* gp, void* lp){
  __builtin_amdgcn_global_load_lds((const __attribute__((address_space(1))) void*)gp,
                                   (__attribute__((address_space(3))) void*)lp,
                                   16, 0, 0);
}

// ---------------- prep kernel: weight repack + dtype detect into d_ws ----------------
// ws[0      .. 65536): W1T bf16, row n = g*64+h (256 rows x 256B), byte = n*256 + (k*2 ^ ((n&7)<<4))
// ws[65536  .. 73728): W2T bf16, row t = g*16+p (64 rows x 128B), byte = t*128 + (h*2 ^ ((t&7)<<4)), p>=4 zeros
// ws[73728]: gshift (0=int32 gids, 1=int64 gids) ; ws[73732]: mshift (0=byte mask, 2=int32 mask)
__global__ void prep_kernel(const float* __restrict__ W1, const float* __restrict__ W2,
                            const void* __restrict__ gids_raw, const void* __restrict__ mask_raw,
                            unsigned char* __restrict__ ws){
  int tid = threadIdx.x, bid = blockIdx.x;
  if (bid < 16){
    int chunk = bid*256 + tid;     // 0..4095 : one 16B chunk of W1T each
    int n    = chunk >> 4;         // 0..255  (col = g*64+h)
    int kb16 = chunk & 15;         // which 16B chunk within the 256B row
    int d0   = kb16 * 8;
    int g = n >> 6, h = n & 63;
    u16x8 v;
#pragma unroll
    for (int j=0;j<8;++j){
      float f = W1[((g*DIM) + d0 + j)*HID + h];
      v[j] = cvbf(f);
    }
    unsigned off = (unsigned)n*256 + (((unsigned)kb16*16) ^ (((unsigned)(n&7))<<4));
    *(u16x8*)(ws + off) = v;
  } else {
#pragma unroll
    for (int i=0;i<16;++i){
      int e = tid + i*256;         // 0..4095 bf16 elements of W2T
      int t = e >> 6;              // 0..63 (g*16+p)
      int h = e & 63;
      int g = t >> 4, p = t & 15;
      float f = (p < NP) ? W2[(g*HID + h)*NP + p] : 0.0f;
      unsigned off = 65536u + (unsigned)t*128 + (((unsigned)(h*2)) ^ (((unsigned)(t&7))<<4));
      *(unsigned short*)(ws + off) = cvbf(f);
    }
    // ---- dtype detection (wave 0) ----
    if (tid < 64){
      const int* g32 = (const int*)gids_raw;
      int accg = 0;
#pragma unroll
      for (int i=0;i<8;++i) accg |= g32[(tid*8 + i)*2 + 1];   // odd int32 words, 512 total
      const unsigned char* m8 = (const unsigned char*)mask_raw;
      int accm = 0;
#pragma unroll
      for (int i=0;i<16;++i){
        int off = tid*16 + i;                                  // bytes 0..1023
        if (off & 3) accm |= m8[off];
      }
      unsigned long long bg = __ballot(accg != 0);
      unsigned long long bm = __ballot(accm != 0);
      if (tid == 0){
        *(int*)(ws + 73728) = (bg == 0ull) ? 1 : 0;   // gshift
        *(int*)(ws + 73732) = (bm == 0ull) ? 2 : 0;   // mshift
      }
    }
  }
}

// ---------------- main kernel ----------------
#define LDS_W2T 65536
#define LDS_B1  (65536+8192)
#define LDS_TOTAL (65536+8192+1024)

__global__ __launch_bounds__(256, 2)
void actor_kernel(const float* __restrict__ X, const int* __restrict__ gids,
                  const unsigned char* __restrict__ fmask,
                  const float* __restrict__ b1, const float* __restrict__ b2,
                  const unsigned char* __restrict__ ws, float* __restrict__ out){
  __shared__ char smem[LDS_TOTAL];
  const int tid  = threadIdx.x;
  const int wave = tid >> 6, lane = tid & 63;
  const int q    = lane >> 4, rS = lane & 15;
  const long blockRow = (long)blockIdx.x * 128;
  const int wrow = wave * 32;
  const int swzA = (rS & 7) << 4;

  // dtype flags from prep (uniform scalar loads)
  const int gshift = *(const int*)(ws + 73728);
  const int mshift = *(const int*)(ws + 73732);

  // --- stage weights+b1 to LDS (async, linear dest; sources pre-swizzled) ---
#pragma unroll
  for (int i=0;i<16;++i){
    int off = i*4096 + wave*1024;
    ldsload16(ws + off + lane*16, smem + off);
  }
#pragma unroll
  for (int i=0;i<2;++i){
    int off = i*4096 + wave*1024;
    ldsload16(ws + 65536 + off + lane*16, smem + LDS_W2T + off);
  }
  if (wave == 0)
    ldsload16((const unsigned char*)b1 + lane*16, smem + LDS_B1);

  // --- load this wave's 32 X rows into registers, convert to bf16 B-fragments ---
  s16x8 bfr[2][4];
#pragma unroll
  for (int nt=0;nt<2;++nt){
    const float* xp = X + (blockRow + wrow + nt*16 + rS) * (long)DIM;
#pragma unroll
    for (int k=0;k<4;++k){
      f32x4 a = *(const f32x4*)(xp + k*32 + q*8);
      f32x4 b = *(const f32x4*)(xp + k*32 + q*8 + 4);
      s16x8 v;
#pragma unroll
      for (int j=0;j<4;++j){ v[j] = (short)cvbf(a[j]); v[j+4] = (short)cvbf(b[j]); }
      bfr[nt][k] = v;
    }
  }

  f32x4 acc[16][2];
#pragma unroll
  for (int mt=0;mt<16;++mt)
#pragma unroll
    for (int nt=0;nt<2;++nt)
      acc[mt][nt] = (f32x4){0.f,0.f,0.f,0.f};

  __syncthreads();   // weights resident

  // --- GEMM1: C^T tile = W1T(A) x X^T(B); M = 256 hidden cols, N = 32 rows ---
#pragma unroll
  for (int k=0;k<4;++k){
#pragma unroll
    for (int mt=0;mt<16;++mt){
      const s16x8 a = *(const s16x8*)(smem + (mt*16 + rS)*256 + ((k*64 + q*16) ^ swzA));
      acc[mt][0] = __builtin_amdgcn_mfma_f32_16x16x32_bf16(a, bfr[0][k], acc[mt][0], 0,0,0);
      acc[mt][1] = __builtin_amdgcn_mfma_f32_16x16x32_bf16(a, bfr[1][k], acc[mt][1], 0,0,0);
    }
  }
  __syncthreads();   // all waves done reading W1T before overwrite

  // --- epilogue1: +b1, relu, ->bf16, write hidden [128 rows][256 cols] (swizzled) over W1T region ---
#pragma unroll
  for (int mt=0;mt<16;++mt){
    const f32x4 b1v = *(const f32x4*)(smem + LDS_B1 + mt*64 + q*16);
#pragma unroll
    for (int nt=0;nt<2;++nt){
      f32x4 v = acc[mt][nt] + b1v;
#pragma unroll
      for (int j=0;j<4;++j) v[j] = v[j] > 0.f ? v[j] : 0.f;
      unsigned lo = (unsigned)cvbf(v[0]) | ((unsigned)cvbf(v[1])<<16);
      unsigned hi = (unsigned)cvbf(v[2]) | ((unsigned)cvbf(v[3])<<16);
      int nl = wrow + nt*16 + rS;                      // local row (C^T col)
      unsigned byte = (unsigned)nl*512 + (unsigned)(mt*32 + q*8);
      byte ^= (unsigned)((nl & 7) << 4);
      u32x2 w; w[0]=lo; w[1]=hi;
      *(u32x2*)(smem + byte) = w;
    }
  }
  __syncthreads();

  // --- GEMM2: logits[row][g][p] = hidden x W2T, dense over 4 groups ---
  s16x8 bw[4][2];
#pragma unroll
  for (int g=0;g<4;++g)
#pragma unroll
    for (int ks=0;ks<2;++ks){
      int t = g*16 + rS;
      bw[g][ks] = *(const s16x8*)(smem + LDS_W2T + t*128 + ((ks*64 + q*16) ^ swzA));
    }
  f32x4 acc2[2][4];
#pragma unroll
  for (int mt=0;mt<2;++mt)
#pragma unroll
    for (int g=0;g<4;++g)
      acc2[mt][g] = (f32x4){0.f,0.f,0.f,0.f};
#pragma unroll
  for (int mt=0;mt<2;++mt){
    int nl = wrow + mt*16 + rS;
    unsigned sw = (unsigned)((nl & 7) << 4);
#pragma unroll
    for (int g=0;g<4;++g)
#pragma unroll
      for (int ks=0;ks<2;++ks){
        unsigned byte = (unsigned)nl*512 + (((unsigned)(g*128 + ks*64 + q*16)) ^ sw);
        s16x8 a = *(const s16x8*)(smem + byte);
        acc2[mt][g] = __builtin_amdgcn_mfma_f32_16x16x32_bf16(a, bw[g][ks], acc2[mt][g], 0,0,0);
      }
  }

  // --- epilogue2: select group, +b2, mask, quad softmax, store ---
#pragma unroll
  for (int mt=0;mt<2;++mt){
#pragma unroll
    for (int r=0;r<4;++r){
      long row = blockRow + wrow + mt*16 + q*4 + r;
      int g = gids[(size_t)row << gshift];              // int64 -> lo word
      float logit =            acc2[mt][0][r];
      logit = (g==1) ? acc2[mt][1][r] : logit;
      logit = (g==2) ? acc2[mt][2][r] : logit;
      logit = (g==3) ? acc2[mt][3][r] : logit;
      float li = -3e9f;
      if (rS < NP){
        float b2v = b2[g*NP + rS];
        unsigned char fe = fmask[(size_t)(row*4 + rS) << mshift];  // int32 -> lo byte
        li = fe ? (logit + b2v) : -1e9f;
      }
      float m = fmaxf(li, __shfl_xor(li, 1));
      m = fmaxf(m, __shfl_xor(m, 2));
      float e = __expf(li - m);
      float s = e + __shfl_xor(e, 1);
      s = s + __shfl_xor(s, 2);
      if (rS < NP) out[row*4 + rS] = e / s;
    }
  }
}

extern "C" void kernel_launch(void* const* d_in, const int* in_sizes, int n_in,
                              void* d_out, int out_size, void* d_ws, size_t ws_size,
                              hipStream_t stream){
  const float* X  = (const float*)d_in[0];
  const void*  gi = d_in[1];
  const void*  fm = d_in[2];
  const float* W1 = (const float*)d_in[3];
  const float* b1 = (const float*)d_in[4];
  const float* W2 = (const float*)d_in[5];
  const float* b2 = (const float*)d_in[6];
  unsigned char* ws = (unsigned char*)d_ws;
  float* out = (float*)d_out;

  prep_kernel<<<dim3(17), dim3(256), 0, stream>>>(W1, W2, gi, fm, ws);
  actor_kernel<<<dim3(NROWS/128), dim3(256), 0, stream>>>(X, (const int*)gi,
                                                          (const unsigned char*)fm,
                                                          b1, b2, ws, out);
}